// Round 4
// baseline (169.369 us; speedup 1.0000x reference)
//
#include <hip/hip_runtime.h>

// B=4, C=256, CR=64, H=W=64, K=7, KK=49, GROUPS=16, GC=16
#define BN_EPS 1e-5f

typedef __bf16 bf16_t;
typedef __bf16 bf16x8 __attribute__((ext_vector_type(8)));
typedef __bf16 bf16x4 __attribute__((ext_vector_type(4)));
typedef float  floatx4 __attribute__((ext_vector_type(4)));

#define MFMA16(a, b, c) __builtin_amdgcn_mfma_f32_16x16x32_bf16((a), (b), (c), 0, 0, 0)

// ws layout
#define GT_OFF  0            // 4*4096*256 bf16 = 8 MB  (guide transposed, c-contig)
#define W1B_OFF 8388608      // 64*256 bf16
#define W2B_OFF 8421376      // 784*64 bf16
#define B1_OFF  8521728      // 64 fp32

// ---------------------------------------------------------------------------
// stage: blocks [0,1024): transpose guide -> bf16 gT[b][p][c] (c-contiguous).
//        blocks [1024,1284): fold BN into w1 (bf16), w2 -> bf16, bias1.
// ---------------------------------------------------------------------------
__global__ __launch_bounds__(256) void stage(
    const float* __restrict__ guide, const float* __restrict__ w1,
    const float* __restrict__ gamma, const float* __restrict__ beta,
    const float* __restrict__ mean,  const float* __restrict__ var,
    const float* __restrict__ w2,
    bf16_t* __restrict__ gT, bf16_t* __restrict__ w1b,
    bf16_t* __restrict__ w2b, float* __restrict__ bias1)
{
    if (blockIdx.x >= 1024) {
        const int idx = (blockIdx.x - 1024) * 256 + threadIdx.x;
        if (idx < 16384) {
            const int o = idx >> 8;
            const float inv = gamma[o] * rsqrtf(var[o] + BN_EPS);
            w1b[idx] = (bf16_t)(w1[idx] * inv);
            if (idx < 64) {
                const float iv = gamma[idx] * rsqrtf(var[idx] + BN_EPS);
                bias1[idx] = beta[idx] - mean[idx] * iv;
            }
        } else if (idx < 16384 + 50176) {
            const int j = idx - 16384;
            w2b[j] = (bf16_t)w2[j];
        }
        return;
    }
    // transpose one (b, h, 64-channel-quad) tile: 64 c x 64 p
    __shared__ float ls[64][65];
    const int cq = blockIdx.x & 3;
    const int bh = blockIdx.x >> 2;         // b*64 + h
    const int b = bh >> 6, h = bh & 63;
    const int t = threadIdx.x;
    const int p = t & 63, c0 = t >> 6;

    const float* src = guide + ((size_t)(b * 256 + cq * 64) * 64 + h) * 64;
#pragma unroll
    for (int i = 0; i < 16; ++i) {
        const int cc = c0 + i * 4;
        ls[cc][p] = src[(size_t)cc * 4096 + p];
    }
    __syncthreads();
#pragma unroll
    for (int i = 0; i < 2; ++i) {
        const int u = i * 256 + t;
        const int pp = u >> 3, c8 = u & 7;
        bf16x8 v;
#pragma unroll
        for (int j = 0; j < 8; ++j) v[j] = (bf16_t)ls[c8 * 8 + j][pp];
        *(bf16x8*)(gT + ((size_t)(b * 4096 + h * 64 + pp)) * 256 + cq * 64 + c8 * 8) = v;
    }
}

// ---------------------------------------------------------------------------
// fused: one block = (b, h-pair, group). grid 2048, 5 blocks/CU resident.
// blockIdx swizzle: band = blockIdx&7 -> XCD (round-robin heuristic); each
// band owns 16 contiguous bh (one b, 32 h rows) x all 16 groups -> gT and
// feature windows are L2-resident per XCD.
//  conv1 (MFMA, contiguous gT frags) -> xsT[128p][64c] bf16 in LDS
//  Phase B MFMA wg[49k][128p] -> wgs bf16 LDS; Phase C fp32 agg + residual.
// ---------------------------------------------------------------------------
#define XSP 72    // bf16 pitch
#define WGP 132   // bf16 pitch

__global__ __launch_bounds__(256, 5) void fused(
    const bf16_t* __restrict__ gT,  const bf16_t* __restrict__ w1b,
    const float* __restrict__ bias1, const bf16_t* __restrict__ w2b,
    const float* __restrict__ b2,    const float* __restrict__ feat,
    float* __restrict__ out)
{
    __shared__ __attribute__((aligned(16))) bf16_t xsT[128 * XSP];  // 18.0 KB
    __shared__ __attribute__((aligned(16))) bf16_t wgs[49 * WGP];   // 12.9 KB

    const int band = blockIdx.x & 7;
    const int rest = blockIdx.x >> 3;       // 0..255
    const int g    = rest >> 4;             // 0..15
    const int bh   = band * 16 + (rest & 15);
    const int b  = bh >> 5;
    const int h0 = (bh & 31) * 2;
    const int t  = threadIdx.x;
    const int wv = t >> 6, ln = t & 63, l15 = ln & 15, q = ln >> 4;

    // ---- conv1 in-block: x[o][p] = ReLU(w1b . gT + bias1) -> xsT[p][o]
    {
        floatx4 acc[4][2] = {};
        const bf16_t* gbase = gT + ((size_t)b * 4096 + h0 * 64) * 256;
#pragma unroll
        for (int ks = 0; ks < 8; ++ks) {
            const bf16x8 bf0 = *(const bf16x8*)(gbase + (size_t)(wv * 32 + l15) * 256 + ks * 32 + q * 8);
            const bf16x8 bf1 = *(const bf16x8*)(gbase + (size_t)(wv * 32 + 16 + l15) * 256 + ks * 32 + q * 8);
#pragma unroll
            for (int mt = 0; mt < 4; ++mt) {
                const bf16x8 a = *(const bf16x8*)(w1b + (mt * 16 + l15) * 256 + ks * 32 + q * 8);
                acc[mt][0] = MFMA16(a, bf0, acc[mt][0]);
                acc[mt][1] = MFMA16(a, bf1, acc[mt][1]);
            }
        }
#pragma unroll
        for (int mt = 0; mt < 4; ++mt) {
            float bi[4];
#pragma unroll
            for (int j = 0; j < 4; ++j) bi[j] = bias1[mt * 16 + q * 4 + j];
#pragma unroll
            for (int nt = 0; nt < 2; ++nt) {
                const int p = wv * 32 + nt * 16 + l15;
                bf16x4 v;
#pragma unroll
                for (int j = 0; j < 4; ++j)
                    v[j] = (bf16_t)fmaxf(acc[mt][nt][j] + bi[j], 0.f);
                *(bf16x4*)&xsT[p * XSP + mt * 16 + q * 4] = v;
            }
        }
    }
    __syncthreads();

    // ---- Phase B: wg[k][p] = w2g . x (+b2) -> wgs bf16 ----
    {
        floatx4 acc[4][2] = {};
#pragma unroll
        for (int ks = 0; ks < 2; ++ks) {
            bf16x8 bfr[2];
#pragma unroll
            for (int nt = 0; nt < 2; ++nt) {
                const int p = wv * 32 + nt * 16 + l15;
                bfr[nt] = *(const bf16x8*)&xsT[p * XSP + ks * 32 + q * 8];
            }
#pragma unroll
            for (int mt = 0; mt < 4; ++mt) {
                int row = g * 49 + mt * 16 + l15;
                row = row > 783 ? 783 : row;   // pad rows: never stored
                const bf16x8 a = *(const bf16x8*)(w2b + row * 64 + ks * 32 + q * 8);
                acc[mt][0] = MFMA16(a, bfr[0], acc[mt][0]);
                acc[mt][1] = MFMA16(a, bfr[1], acc[mt][1]);
            }
        }
#pragma unroll
        for (int mt = 0; mt < 4; ++mt) {
#pragma unroll
            for (int j = 0; j < 4; ++j) {
                const int k = mt * 16 + q * 4 + j;
                if (k < 49) {
                    const float bias = b2[g * 49 + k];
#pragma unroll
                    for (int nt = 0; nt < 2; ++nt) {
                        const int p = wv * 32 + nt * 16 + l15;
                        wgs[k * WGP + p] = (bf16_t)(acc[mt][nt][j] + bias);
                    }
                }
            }
        }
    }
    __syncthreads();

    // ---- Phase C: aggregation + residual (fp32) ----
    {
        const int wq = t & 15, r = (t >> 4) & 1, cp = t >> 5;  // cp in [0,8)
        const int w0 = wq * 4;
        const int ch0 = g * 16 + cp * 2;
        const int hr = h0 + r;
        float a0[4] = {0.f, 0.f, 0.f, 0.f}, a1[4] = {0.f, 0.f, 0.f, 0.f};
        float4 q0 = {0, 0, 0, 0}, q1 = {0, 0, 0, 0};  // residual, captured at di==3
#pragma unroll
        for (int di = 0; di < 7; ++di) {
            const int hh = hr + di - 3;
            if (hh < 0 || hh >= 64) continue;   // di==3 always in range
            const float* r0 = feat + ((size_t)(b * 256 + ch0) * 64 + hh) * 64;
            const float* r1 = r0 + 4096;
            float4 L0 = {0,0,0,0}, L1 = {0,0,0,0}, R0 = {0,0,0,0}, R1 = {0,0,0,0};
            if (wq > 0)  { L0 = *(const float4*)(r0 + w0 - 4); L1 = *(const float4*)(r1 + w0 - 4); }
            const float4 M0 = *(const float4*)(r0 + w0);
            const float4 M1 = *(const float4*)(r1 + w0);
            if (wq < 15) { R0 = *(const float4*)(r0 + w0 + 4); R1 = *(const float4*)(r1 + w0 + 4); }
            if (di == 3) { q0 = M0; q1 = M1; }
            float f0[10], f1[10];
            f0[0]=L0.y; f0[1]=L0.z; f0[2]=L0.w; f0[3]=M0.x; f0[4]=M0.y;
            f0[5]=M0.z; f0[6]=M0.w; f0[7]=R0.x; f0[8]=R0.y; f0[9]=R0.z;
            f1[0]=L1.y; f1[1]=L1.z; f1[2]=L1.w; f1[3]=M1.x; f1[4]=M1.y;
            f1[5]=M1.z; f1[6]=M1.w; f1[7]=R1.x; f1[8]=R1.y; f1[9]=R1.z;
            const bf16_t* wrow = &wgs[(di * 7) * WGP + r * 64 + w0];
#pragma unroll
            for (int dj = 0; dj < 7; ++dj) {
                const bf16x4 wb = *(const bf16x4*)(wrow + dj * WGP);
#pragma unroll
                for (int x = 0; x < 4; ++x) {
                    const float wf = (float)wb[x];
                    a0[x] = fmaf(wf, f0[x + dj], a0[x]);
                    a1[x] = fmaf(wf, f1[x + dj], a1[x]);
                }
            }
        }
        const size_t ob = ((size_t)(b * 256 + ch0) * 64 + hr) * 64 + w0;
        float4 o0, o1;
        o0.x = a0[0] + q0.x; o0.y = a0[1] + q0.y; o0.z = a0[2] + q0.z; o0.w = a0[3] + q0.w;
        o1.x = a1[0] + q1.x; o1.y = a1[1] + q1.y; o1.z = a1[2] + q1.z; o1.w = a1[3] + q1.w;
        *(float4*)(out + ob) = o0;
        *(float4*)(out + ob + 4096) = o1;
    }
}

extern "C" void kernel_launch(void* const* d_in, const int* in_sizes, int n_in,
                              void* d_out, int out_size, void* d_ws, size_t ws_size,
                              hipStream_t stream) {
    const float* feature = (const float*)d_in[0];
    const float* guide   = (const float*)d_in[1];
    const float* w1      = (const float*)d_in[2];
    const float* gamma   = (const float*)d_in[3];
    const float* beta    = (const float*)d_in[4];
    const float* mean    = (const float*)d_in[5];
    const float* var     = (const float*)d_in[6];
    const float* w2      = (const float*)d_in[7];
    const float* b2      = (const float*)d_in[8];
    float* out = (float*)d_out;

    char* ws = (char*)d_ws;
    bf16_t* gT    = (bf16_t*)(ws + GT_OFF);
    bf16_t* w1b   = (bf16_t*)(ws + W1B_OFF);
    bf16_t* w2b   = (bf16_t*)(ws + W2B_OFF);
    float*  bias1 = (float*) (ws + B1_OFF);

    stage<<<1284, 256, 0, stream>>>(guide, w1, gamma, beta, mean, var, w2,
                                    gT, w1b, w2b, bias1);
    fused<<<2048, 256, 0, stream>>>(gT, w1b, bias1, w2b, b2, feature, out);
}

// Round 5
// 141.167 us; speedup vs baseline: 1.1998x; 1.1998x over previous
//
#include <hip/hip_runtime.h>

// B=4, C=256, CR=64, H=W=64, K=7, KK=49, GROUPS=16, GC=16
#define BN_EPS 1e-5f

typedef __bf16 bf16_t;
typedef __bf16 bf16x8 __attribute__((ext_vector_type(8)));
typedef __bf16 bf16x4 __attribute__((ext_vector_type(4)));
typedef float  floatx4 __attribute__((ext_vector_type(4)));

#define MFMA16(a, b, c) __builtin_amdgcn_mfma_f32_16x16x32_bf16((a), (b), (c), 0, 0, 0)

// ws layout
#define GT_OFF  0            // 4*4096*256 bf16 = 8 MB  (guide transposed, c-contig)
#define W1B_OFF 8388608      // 64*256 bf16
#define W2B_OFF 8421376      // 784*64 bf16
#define B1_OFF  8521728      // 64 fp32

// ---------------------------------------------------------------------------
// stage: blocks [0,1024): transpose guide -> bf16 gT[b][p][c] (c-contiguous).
//        blocks [1024,1284): fold BN into w1 (bf16), w2 -> bf16, bias1.
// ---------------------------------------------------------------------------
__global__ __launch_bounds__(256) void stage(
    const float* __restrict__ guide, const float* __restrict__ w1,
    const float* __restrict__ gamma, const float* __restrict__ beta,
    const float* __restrict__ mean,  const float* __restrict__ var,
    const float* __restrict__ w2,
    bf16_t* __restrict__ gT, bf16_t* __restrict__ w1b,
    bf16_t* __restrict__ w2b, float* __restrict__ bias1)
{
    if (blockIdx.x >= 1024) {
        const int idx = (blockIdx.x - 1024) * 256 + threadIdx.x;
        if (idx < 16384) {
            const int o = idx >> 8;
            const float inv = gamma[o] * rsqrtf(var[o] + BN_EPS);
            w1b[idx] = (bf16_t)(w1[idx] * inv);
            if (idx < 64) {
                const float iv = gamma[idx] * rsqrtf(var[idx] + BN_EPS);
                bias1[idx] = beta[idx] - mean[idx] * iv;
            }
        } else if (idx < 16384 + 50176) {
            const int j = idx - 16384;
            w2b[j] = (bf16_t)w2[j];
        }
        return;
    }
    // transpose one (b, h, 64-channel-quad) tile: 64 c x 64 p
    __shared__ float ls[64][65];
    const int cq = blockIdx.x & 3;
    const int bh = blockIdx.x >> 2;         // b*64 + h
    const int b = bh >> 6, h = bh & 63;
    const int t = threadIdx.x;
    const int p = t & 63, c0 = t >> 6;

    const float* src = guide + ((size_t)(b * 256 + cq * 64) * 64 + h) * 64;
#pragma unroll
    for (int i = 0; i < 16; ++i) {
        const int cc = c0 + i * 4;
        ls[cc][p] = src[(size_t)cc * 4096 + p];
    }
    __syncthreads();
#pragma unroll
    for (int i = 0; i < 2; ++i) {
        const int u = i * 256 + t;
        const int pp = u >> 3, c8 = u & 7;
        bf16x8 v;
#pragma unroll
        for (int j = 0; j < 8; ++j) v[j] = (bf16_t)ls[c8 * 8 + j][pp];
        *(bf16x8*)(gT + ((size_t)(b * 4096 + h * 64 + pp)) * 256 + cq * 64 + c8 * 8) = v;
    }
}

// ---------------------------------------------------------------------------
// fused: one block = (b, h-pair, g-PAIR). grid 1024 = 4 blocks/CU, ALL
// co-resident. gp = blockIdx&7 -> XCD partition by channel-pair: each XCD
// reads only its 32 feat channels (2 MB working set, L2-resident) + shared gT.
//  conv1 (MFMA, contiguous gT frags) -> xsT[128p][64c] bf16 in LDS  (8x redundant)
//  2x groups: Phase B MFMA wg[49k][128p] -> wgs bf16; Phase C fp32 agg + residual.
// ---------------------------------------------------------------------------
#define XSP 72    // bf16 pitch
#define WGP 132   // bf16 pitch

__global__ __launch_bounds__(256, 4) void fused(
    const bf16_t* __restrict__ gT,  const bf16_t* __restrict__ w1b,
    const float* __restrict__ bias1, const bf16_t* __restrict__ w2b,
    const float* __restrict__ b2,    const float* __restrict__ feat,
    float* __restrict__ out)
{
    __shared__ __attribute__((aligned(16))) bf16_t xsT[128 * XSP];  // 18.0 KB
    __shared__ __attribute__((aligned(16))) bf16_t wgs[49 * WGP];   // 12.9 KB

    const int gp = blockIdx.x & 7;          // g-pair id == XCD partition
    const int bh = blockIdx.x >> 3;         // 0..127
    const int b  = bh >> 5;
    const int h0 = (bh & 31) * 2;
    const int t  = threadIdx.x;
    const int wv = t >> 6, ln = t & 63, l15 = ln & 15, q = ln >> 4;

    // ---- conv1 in-block: x[o][p] = ReLU(w1b . gT + bias1) -> xsT[p][o]
    {
        floatx4 acc[4][2] = {};
        const bf16_t* gbase = gT + ((size_t)b * 4096 + h0 * 64) * 256;
#pragma unroll
        for (int ks = 0; ks < 8; ++ks) {
            const bf16x8 bf0 = *(const bf16x8*)(gbase + (size_t)(wv * 32 + l15) * 256 + ks * 32 + q * 8);
            const bf16x8 bf1 = *(const bf16x8*)(gbase + (size_t)(wv * 32 + 16 + l15) * 256 + ks * 32 + q * 8);
#pragma unroll
            for (int mt = 0; mt < 4; ++mt) {
                const bf16x8 a = *(const bf16x8*)(w1b + (mt * 16 + l15) * 256 + ks * 32 + q * 8);
                acc[mt][0] = MFMA16(a, bf0, acc[mt][0]);
                acc[mt][1] = MFMA16(a, bf1, acc[mt][1]);
            }
        }
#pragma unroll
        for (int mt = 0; mt < 4; ++mt) {
            float bi[4];
#pragma unroll
            for (int j = 0; j < 4; ++j) bi[j] = bias1[mt * 16 + q * 4 + j];
#pragma unroll
            for (int nt = 0; nt < 2; ++nt) {
                const int p = wv * 32 + nt * 16 + l15;
                bf16x4 v;
#pragma unroll
                for (int j = 0; j < 4; ++j)
                    v[j] = (bf16_t)fmaxf(acc[mt][nt][j] + bi[j], 0.f);
                *(bf16x4*)&xsT[p * XSP + mt * 16 + q * 4] = v;
            }
        }
    }
    __syncthreads();

    for (int gi = 0; gi < 2; ++gi) {
        const int g = gp * 2 + gi;
        if (gi) __syncthreads();          // prior Phase C done before wgs reuse

        // ---- Phase B: wg[k][p] = w2g . x (+b2) -> wgs bf16 ----
        {
            floatx4 acc[4][2] = {};
#pragma unroll
            for (int ks = 0; ks < 2; ++ks) {
                bf16x8 bfr[2];
#pragma unroll
                for (int nt = 0; nt < 2; ++nt) {
                    const int p = wv * 32 + nt * 16 + l15;
                    bfr[nt] = *(const bf16x8*)&xsT[p * XSP + ks * 32 + q * 8];
                }
#pragma unroll
                for (int mt = 0; mt < 4; ++mt) {
                    int row = g * 49 + mt * 16 + l15;
                    row = row > 783 ? 783 : row;   // pad rows: never stored
                    const bf16x8 a = *(const bf16x8*)(w2b + row * 64 + ks * 32 + q * 8);
                    acc[mt][0] = MFMA16(a, bfr[0], acc[mt][0]);
                    acc[mt][1] = MFMA16(a, bfr[1], acc[mt][1]);
                }
            }
#pragma unroll
            for (int mt = 0; mt < 4; ++mt) {
#pragma unroll
                for (int j = 0; j < 4; ++j) {
                    const int k = mt * 16 + q * 4 + j;
                    if (k < 49) {
                        const float bias = b2[g * 49 + k];
#pragma unroll
                        for (int nt = 0; nt < 2; ++nt) {
                            const int p = wv * 32 + nt * 16 + l15;
                            wgs[k * WGP + p] = (bf16_t)(acc[mt][nt][j] + bias);
                        }
                    }
                }
            }
        }
        __syncthreads();

        // ---- Phase C: aggregation + residual (fp32) ----
        {
            const int wq = t & 15, r = (t >> 4) & 1, cp = t >> 5;  // cp in [0,8)
            const int w0 = wq * 4;
            const int ch0 = g * 16 + cp * 2;
            const int hr = h0 + r;
            float a0[4] = {0.f, 0.f, 0.f, 0.f}, a1[4] = {0.f, 0.f, 0.f, 0.f};
            float4 q0 = {0, 0, 0, 0}, q1 = {0, 0, 0, 0};  // residual, captured at di==3
#pragma unroll
            for (int di = 0; di < 7; ++di) {
                const int hh = hr + di - 3;
                if (hh < 0 || hh >= 64) continue;   // di==3 always in range
                const float* r0 = feat + ((size_t)(b * 256 + ch0) * 64 + hh) * 64;
                const float* r1 = r0 + 4096;
                float4 L0 = {0,0,0,0}, L1 = {0,0,0,0}, R0 = {0,0,0,0}, R1 = {0,0,0,0};
                if (wq > 0)  { L0 = *(const float4*)(r0 + w0 - 4); L1 = *(const float4*)(r1 + w0 - 4); }
                const float4 M0 = *(const float4*)(r0 + w0);
                const float4 M1 = *(const float4*)(r1 + w0);
                if (wq < 15) { R0 = *(const float4*)(r0 + w0 + 4); R1 = *(const float4*)(r1 + w0 + 4); }
                if (di == 3) { q0 = M0; q1 = M1; }
                float f0[10], f1[10];
                f0[0]=L0.y; f0[1]=L0.z; f0[2]=L0.w; f0[3]=M0.x; f0[4]=M0.y;
                f0[5]=M0.z; f0[6]=M0.w; f0[7]=R0.x; f0[8]=R0.y; f0[9]=R0.z;
                f1[0]=L1.y; f1[1]=L1.z; f1[2]=L1.w; f1[3]=M1.x; f1[4]=M1.y;
                f1[5]=M1.z; f1[6]=M1.w; f1[7]=R1.x; f1[8]=R1.y; f1[9]=R1.z;
                const bf16_t* wrow = &wgs[(di * 7) * WGP + r * 64 + w0];
#pragma unroll
                for (int dj = 0; dj < 7; ++dj) {
                    const bf16x4 wb = *(const bf16x4*)(wrow + dj * WGP);
#pragma unroll
                    for (int x = 0; x < 4; ++x) {
                        const float wf = (float)wb[x];
                        a0[x] = fmaf(wf, f0[x + dj], a0[x]);
                        a1[x] = fmaf(wf, f1[x + dj], a1[x]);
                    }
                }
            }
            const size_t ob = ((size_t)(b * 256 + ch0) * 64 + hr) * 64 + w0;
            float4 o0, o1;
            o0.x = a0[0] + q0.x; o0.y = a0[1] + q0.y; o0.z = a0[2] + q0.z; o0.w = a0[3] + q0.w;
            o1.x = a1[0] + q1.x; o1.y = a1[1] + q1.y; o1.z = a1[2] + q1.z; o1.w = a1[3] + q1.w;
            *(float4*)(out + ob) = o0;
            *(float4*)(out + ob + 4096) = o1;
        }
    }
}

extern "C" void kernel_launch(void* const* d_in, const int* in_sizes, int n_in,
                              void* d_out, int out_size, void* d_ws, size_t ws_size,
                              hipStream_t stream) {
    const float* feature = (const float*)d_in[0];
    const float* guide   = (const float*)d_in[1];
    const float* w1      = (const float*)d_in[2];
    const float* gamma   = (const float*)d_in[3];
    const float* beta    = (const float*)d_in[4];
    const float* mean    = (const float*)d_in[5];
    const float* var     = (const float*)d_in[6];
    const float* w2      = (const float*)d_in[7];
    const float* b2      = (const float*)d_in[8];
    float* out = (float*)d_out;

    char* ws = (char*)d_ws;
    bf16_t* gT    = (bf16_t*)(ws + GT_OFF);
    bf16_t* w1b   = (bf16_t*)(ws + W1B_OFF);
    bf16_t* w2b   = (bf16_t*)(ws + W2B_OFF);
    float*  bias1 = (float*) (ws + B1_OFF);

    stage<<<1284, 256, 0, stream>>>(guide, w1, gamma, beta, mean, var, w2,
                                    gT, w1b, w2b, bias1);
    fused<<<1024, 256, 0, stream>>>(gT, w1b, bias1, w2b, b2, feature, out);
}